// Round 5
// baseline (300.917 us; speedup 1.0000x reference)
//
#include <hip/hip_runtime.h>
#include <math.h>

#define NB 64
#define NS 512
#define NH 768
#define NT 3
#define EMIS_N (NB * NS * NT)   // 98304
#define NEGINF (-1e30f)
#define WPB 128                 // waves per batch (512 rows / 4)
#define PSTRIDE 12              // floats per wave partial in ws
#define NBLK 2048

__device__ __forceinline__ float lse3(float a, float b, float c) {
    float m = fmaxf(fmaxf(a, b), c);
    return m + __logf(__expf(a - m) + __expf(b - m) + __expf(c - m));
}

// ---------------------------------------------------------------------------
// Single fused kernel:
//  phase 1 (all 2048 blocks): emissions = relu(hidden @ W + b), 16 lanes/row,
//    4 rows/wave; wave composes its 4 CRF step matrices (log-semiring) and
//    numerator partial -> 10-float partial in ws.
//  phase 2 (last-finishing block only, via atomic ticket): folds the 128
//    partials of each batch with an ordered shfl tree (16 batches per wave),
//    writes nll to out[EMIS_N]. Ticket test uses (old & 2047)==2047 so the
//    0xAA-poisoned counter needs no init dispatch.
// ---------------------------------------------------------------------------
__global__ __launch_bounds__(256) void fused_emis_crf(
    const float* __restrict__ hidden,   // [NB*NS, NH]
    const int*   __restrict__ labels,   // [NB, NS]
    const int*   __restrict__ mask,     // [NB, NS]
    const float* __restrict__ W,        // [NH, NT]
    const float* __restrict__ bias,     // [NT]
    const float* __restrict__ trans,    // [NT, NT]
    const float* __restrict__ startv,   // [NT]
    const float* __restrict__ endv,     // [NT]
    float* __restrict__ out,            // emissions [NB*NS, NT], then nll
    float* __restrict__ ws,             // [8192][PSTRIDE] partials
    unsigned int* __restrict__ ctr)     // ticket counter (never reset)
{
    const int tid  = threadIdx.x;
    const int lane = tid & 63;
    const int wv   = tid >> 6;
    const int wid  = blockIdx.x * 4 + wv;    // 0..8191
    const int sub  = lane & 15;              // h-chunk within row
    const int rsel = lane >> 4;              // which of the wave's 4 rows
    const int row  = wid * 4 + rsel;
    const int b    = row >> 9;               // batch
    const int p    = row & (NS - 1);         // position in sequence

    const float* hrow = hidden + (size_t)row * NH;

    float a0 = 0.f, a1 = 0.f, a2 = 0.f;
    #pragma unroll
    for (int it = 0; it < 12; ++it) {
        const int h0 = it * 64 + sub * 4;
        const float4 x  = *reinterpret_cast<const float4*>(hrow + h0);
        const float4 q0 = *reinterpret_cast<const float4*>(W + h0 * 3);
        const float4 q1 = *reinterpret_cast<const float4*>(W + h0 * 3 + 4);
        const float4 q2 = *reinterpret_cast<const float4*>(W + h0 * 3 + 8);
        a0 = fmaf(x.x, q0.x, a0); a1 = fmaf(x.x, q0.y, a1); a2 = fmaf(x.x, q0.z, a2);
        a0 = fmaf(x.y, q0.w, a0); a1 = fmaf(x.y, q1.x, a1); a2 = fmaf(x.y, q1.y, a2);
        a0 = fmaf(x.z, q1.z, a0); a1 = fmaf(x.z, q1.w, a1); a2 = fmaf(x.z, q2.x, a2);
        a0 = fmaf(x.w, q2.y, a0); a1 = fmaf(x.w, q2.z, a1); a2 = fmaf(x.w, q2.w, a2);
    }
    #pragma unroll
    for (int d = 8; d; d >>= 1) {
        a0 += __shfl_xor(a0, d);
        a1 += __shfl_xor(a1, d);
        a2 += __shfl_xor(a2, d);
    }

    const float e0 = fmaxf(a0 + bias[0], 0.f);
    const float e1 = fmaxf(a1 + bias[1], 0.f);
    const float e2 = fmaxf(a2 + bias[2], 0.f);

    if (sub < 3) out[row * NT + sub] = (sub == 0) ? e0 : (sub == 1) ? e1 : e2;

    // ---- CRF per-group metadata (sub==0 lanes) ----
    const int* lrow = labels + b * NS;
    const int* mrow = mask   + b * NS;
    int   mk = 0;
    float term = 0.f;
    if (sub == 0) {
        mk = mrow[p];
        const int labc = lrow[p];
        const float esel = (labc == 0) ? e0 : (labc == 1) ? e1 : e2;
        if (p == 0) {
            term = startv[labc] + esel;               // boundary term
        } else if (mk) {
            const int labp = lrow[p - 1];
            term = trans[labp * 3 + labc] + esel;     // step term
        }
    }

    // ---- compose the wave's 4 step matrices (9 active lanes) ----
    const int il = (lane < 9) ? (lane / 3) : 0;
    const int jl = (lane < 9) ? (lane % 3) : 0;
    const float tc0 = trans[jl], tc1 = trans[3 + jl], tc2 = trans[6 + jl];
    float Pv = (il == jl) ? 0.f : NEGINF;

    const int pbase = p & ~3;
    #pragma unroll
    for (int k = 0; k < 4; ++k) {
        const int src = k << 4;
        const float ee0 = __shfl(e0, src);
        const float ee1 = __shfl(e1, src);
        const float ee2 = __shfl(e2, src);
        const int   mm  = __shfl(mk, src);
        const float Pi0 = __shfl(Pv, il * 3 + 0);
        const float Pi1 = __shfl(Pv, il * 3 + 1);
        const float Pi2 = __shfl(Pv, il * 3 + 2);
        const float ej  = (jl == 0) ? ee0 : (jl == 1) ? ee1 : ee2;
        const float q   = lse3(Pi0 + tc0, Pi1 + tc1, Pi2 + tc2) + ej;
        const bool act  = ((pbase + k) >= 1) && (mm != 0);
        Pv = act ? q : Pv;
    }

    const float np = __shfl(term, 0) + __shfl(term, 16) +
                     __shfl(term, 32) + __shfl(term, 48);

    float* wp = ws + wid * PSTRIDE;
    if (lane < 9) wp[lane] = Pv;
    if (lane == 0) wp[9] = np;

    // ---- ticket: exactly one block (the last to arrive) combines ----
    __threadfence();                       // release our ws/out stores
    __shared__ unsigned int s_tkt;
    __syncthreads();
    if (tid == 0) s_tkt = atomicAdd(ctr, 1u);
    __syncthreads();
    if ((s_tkt & (NBLK - 1u)) != (NBLK - 1u)) return;
    __threadfence();                       // acquire others' stores

    // ---- phase 2: combine (4 waves x 16 batches) ----
    __shared__ float s_nll[4];
    float acc = 0.f;

    for (int bb = wv; bb < NB; bb += 4) {
        const int* mrow2 = mask   + bb * NS;
        const int* lrow2 = labels + bb * NS;

        int lsum = 0;
        #pragma unroll
        for (int k = 0; k < 8; ++k) lsum += mrow2[lane + k * 64];
        #pragma unroll
        for (int d = 32; d; d >>= 1) lsum += __shfl_xor(lsum, d);
        const int len = lsum;

        const float* base = ws + (size_t)bb * WPB * PSTRIDE;
        const float* pa = base + (2 * lane)     * PSTRIDE;
        const float* pb = base + (2 * lane + 1) * PSTRIDE;
        float A[9], Bm[9];
        #pragma unroll
        for (int i = 0; i < 9; ++i) A[i]  = pa[i];
        #pragma unroll
        for (int i = 0; i < 9; ++i) Bm[i] = pb[i];
        float np2 = pa[9] + pb[9];

        float P[9];
        #pragma unroll
        for (int i = 0; i < 3; ++i)
            #pragma unroll
            for (int j = 0; j < 3; ++j)
                P[i * 3 + j] = lse3(A[i * 3 + 0] + Bm[0 + j],
                                    A[i * 3 + 1] + Bm[3 + j],
                                    A[i * 3 + 2] + Bm[6 + j]);

        #pragma unroll
        for (int d = 1; d < 64; d <<= 1) {
            float Q[9];
            #pragma unroll
            for (int i = 0; i < 9; ++i) Q[i] = __shfl_down(P[i], d);
            const bool valid = (lane + d) < 64;
            float R[9];
            #pragma unroll
            for (int i = 0; i < 3; ++i)
                #pragma unroll
                for (int j = 0; j < 3; ++j)
                    R[i * 3 + j] = lse3(P[i * 3 + 0] + Q[0 + j],
                                        P[i * 3 + 1] + Q[3 + j],
                                        P[i * 3 + 2] + Q[6 + j]);
            #pragma unroll
            for (int i = 0; i < 9; ++i) P[i] = valid ? R[i] : P[i];
        }

        #pragma unroll
        for (int d = 32; d; d >>= 1) np2 += __shfl_xor(np2, d);

        if (lane == 0) {
            const float* erow = out + (size_t)bb * NS * NT;
            const float b0 = startv[0] + erow[0];
            const float b1 = startv[1] + erow[1];
            const float b2 = startv[2] + erow[2];
            const float f0 = lse3(b0 + P[0], b1 + P[3], b2 + P[6]);
            const float f1 = lse3(b0 + P[1], b1 + P[4], b2 + P[7]);
            const float f2 = lse3(b0 + P[2], b1 + P[5], b2 + P[8]);
            const float logZ = lse3(f0 + endv[0], f1 + endv[1], f2 + endv[2]);
            const int tl = lrow2[len - 1];
            acc += logZ - (np2 + endv[tl]);   // start+e0 term already in np2
        }
    }

    if (lane == 0) s_nll[wv] = acc;
    __syncthreads();
    if (tid == 0) out[EMIS_N] = s_nll[0] + s_nll[1] + s_nll[2] + s_nll[3];
}

extern "C" void kernel_launch(void* const* d_in, const int* in_sizes, int n_in,
                              void* d_out, int out_size, void* d_ws, size_t ws_size,
                              hipStream_t stream) {
    const float* hidden = (const float*)d_in[0];
    const int*   labels = (const int*)  d_in[1];
    const int*   maskp  = (const int*)  d_in[2];
    const float* W      = (const float*)d_in[3];
    const float* bias   = (const float*)d_in[4];
    const float* trans  = (const float*)d_in[5];
    const float* startv = (const float*)d_in[6];
    const float* endv   = (const float*)d_in[7];
    float* out = (float*)d_out;
    float* ws  = (float*)d_ws;                               // 384 KB partials
    unsigned int* ctr = (unsigned int*)(ws + 8192 * PSTRIDE); // ticket counter

    fused_emis_crf<<<NBLK, 256, 0, stream>>>(hidden, labels, maskp, W, bias,
                                             trans, startv, endv, out, ws, ctr);
}

// Round 6
// 29.989 us; speedup vs baseline: 10.0343x; 10.0343x over previous
//
#include <hip/hip_runtime.h>
#include <math.h>

#define NB 64
#define NS 512
#define NH 768
#define NT 3
#define EMIS_N (NB * NS * NT)   // 98304
#define NEGINF (-1e30f)
#define WPB 128                 // waves per batch (512 rows / 4)
#define PSTRIDE 12              // floats per wave partial in ws

typedef __attribute__((address_space(1))) const void glob_void;
typedef __attribute__((address_space(3))) void lds_void;

__device__ __forceinline__ float lse3(float a, float b, float c) {
    float m = fmaxf(fmaxf(a, b), c);
    return m + __logf(__expf(a - m) + __expf(b - m) + __expf(c - m));
}

// ---------------------------------------------------------------------------
// Kernel 1: emissions = relu(hidden @ W + b) fused with per-wave CRF partial.
// Deep-pipelined: all 12 hidden float4 loads issued into a register array
// up front (12 KB/wave outstanding on vmcnt); W staged once to LDS so its 36
// per-lane reads ride lgkmcnt (ds_read_b128, <=2-way bank alias = free).
// One vmcnt(0)+barrier, then stall-free FMA stream. No device fences.
// ---------------------------------------------------------------------------
__global__ __launch_bounds__(256) void emis_crf_kernel(
    const float* __restrict__ hidden,   // [NB*NS, NH]
    const int*   __restrict__ labels,   // [NB, NS]
    const int*   __restrict__ mask,     // [NB, NS]
    const float* __restrict__ W,        // [NH, NT]
    const float* __restrict__ bias,     // [NT]
    const float* __restrict__ trans,    // [NT, NT]
    const float* __restrict__ startv,   // [NT]
    float* __restrict__ out,            // emissions [NB*NS, NT], then nll
    float* __restrict__ ws)             // [8192 waves][PSTRIDE]
{
    __shared__ alignas(16) float wlds[NH * NT];    // 9216 B

    const int tid  = threadIdx.x;
    const int lane = tid & 63;
    const int wv   = tid >> 6;               // wave 0..3
    const int wid  = blockIdx.x * 4 + wv;    // 0..8191
    const int sub  = lane & 15;               // h-chunk within row
    const int rsel = lane >> 4;               // which of the wave's 4 rows
    const int row  = wid * 4 + rsel;
    const int b    = row >> 9;                // batch
    const int p    = row & (NS - 1);          // position in sequence

    if (blockIdx.x == 0 && tid == 0) out[EMIS_N] = 0.0f;   // init nll acc

    // ---- issue ALL hidden loads first (register array, 12 in flight) ----
    const float4* hp = reinterpret_cast<const float4*>(hidden + (size_t)row * NH);
    float4 x[12];
    #pragma unroll
    for (int it = 0; it < 12; ++it) x[it] = hp[it * 16 + sub];

    // ---- stage W to LDS (576 x 16B chunks), overlaps hidden misses ----
    #pragma unroll
    for (int k = 0; k < 3; ++k) {
        const int c = k * 256 + tid;                 // chunk index
        if (c < (NH * NT) / 4) {                     // wave-uniform branch
            __builtin_amdgcn_global_load_lds(
                (glob_void*)(W + (size_t)c * 4),
                (lds_void*)(wlds + (k * 256 + wv * 64) * 4),
                16, 0, 0);
        }
    }

    asm volatile("s_waitcnt vmcnt(0)" ::: "memory");
    __syncthreads();

    // ---- GEMV: FMAs from registers (hidden) x LDS (W) ----
    float a0 = 0.f, a1 = 0.f, a2 = 0.f;
    #pragma unroll
    for (int it = 0; it < 12; ++it) {
        const int h0 = it * 64 + sub * 4;
        const float4 q0 = *reinterpret_cast<const float4*>(wlds + h0 * 3);
        const float4 q1 = *reinterpret_cast<const float4*>(wlds + h0 * 3 + 4);
        const float4 q2 = *reinterpret_cast<const float4*>(wlds + h0 * 3 + 8);
        a0 = fmaf(x[it].x, q0.x, a0); a1 = fmaf(x[it].x, q0.y, a1); a2 = fmaf(x[it].x, q0.z, a2);
        a0 = fmaf(x[it].y, q0.w, a0); a1 = fmaf(x[it].y, q1.x, a1); a2 = fmaf(x[it].y, q1.y, a2);
        a0 = fmaf(x[it].z, q1.z, a0); a1 = fmaf(x[it].z, q1.w, a1); a2 = fmaf(x[it].z, q2.x, a2);
        a0 = fmaf(x[it].w, q2.y, a0); a1 = fmaf(x[it].w, q2.z, a1); a2 = fmaf(x[it].w, q2.w, a2);
    }
    #pragma unroll
    for (int d = 8; d; d >>= 1) {
        a0 += __shfl_xor(a0, d);
        a1 += __shfl_xor(a1, d);
        a2 += __shfl_xor(a2, d);
    }

    const float e0 = fmaxf(a0 + bias[0], 0.f);
    const float e1 = fmaxf(a1 + bias[1], 0.f);
    const float e2 = fmaxf(a2 + bias[2], 0.f);

    if (sub < 3) out[row * NT + sub] = (sub == 0) ? e0 : (sub == 1) ? e1 : e2;

    // ---- CRF per-group metadata (sub==0 lanes) ----
    const int* lrow = labels + b * NS;
    const int* mrow = mask   + b * NS;
    int   mk = 0;
    float term = 0.f;
    if (sub == 0) {
        mk = mrow[p];
        const int labc = lrow[p];
        const float esel = (labc == 0) ? e0 : (labc == 1) ? e1 : e2;
        if (p == 0) {
            term = startv[labc] + esel;               // boundary term
        } else if (mk) {
            const int labp = lrow[p - 1];
            term = trans[labp * 3 + labc] + esel;     // step term
        }
    }

    // ---- compose the wave's 4 step matrices (9 active lanes) ----
    const int il = (lane < 9) ? (lane / 3) : 0;
    const int jl = (lane < 9) ? (lane % 3) : 0;
    const float tc0 = trans[jl], tc1 = trans[3 + jl], tc2 = trans[6 + jl];
    float Pv = (il == jl) ? 0.f : NEGINF;

    const int pbase = p & ~3;
    #pragma unroll
    for (int k = 0; k < 4; ++k) {
        const int src = k << 4;
        const float ee0 = __shfl(e0, src);
        const float ee1 = __shfl(e1, src);
        const float ee2 = __shfl(e2, src);
        const int   mm  = __shfl(mk, src);
        const float Pi0 = __shfl(Pv, il * 3 + 0);
        const float Pi1 = __shfl(Pv, il * 3 + 1);
        const float Pi2 = __shfl(Pv, il * 3 + 2);
        const float ej  = (jl == 0) ? ee0 : (jl == 1) ? ee1 : ee2;
        const float q   = lse3(Pi0 + tc0, Pi1 + tc1, Pi2 + tc2) + ej;
        const bool act  = ((pbase + k) >= 1) && (mm != 0);
        Pv = act ? q : Pv;
    }

    const float np = __shfl(term, 0) + __shfl(term, 16) +
                     __shfl(term, 32) + __shfl(term, 48);

    float* wp = ws + wid * PSTRIDE;
    if (lane < 9) wp[lane] = Pv;
    if (lane == 0) wp[9] = np;
}

// ---------------------------------------------------------------------------
// Kernel 2: combiner. One 64-lane block per batch: fold 2 wave partials per
// lane, 6-step ordered shfl tree, boundary terms, one atomicAdd per batch.
// ---------------------------------------------------------------------------
__global__ __launch_bounds__(64) void crf_combine(
    const float* __restrict__ emis,     // [NB*NS, NT] (= d_out)
    const int*   __restrict__ labels,   // [NB, NS]
    const int*   __restrict__ mask,     // [NB, NS]
    const float* __restrict__ startv,   // [NT]
    const float* __restrict__ endv,     // [NT]
    const float* __restrict__ ws,       // wave partials
    float* __restrict__ nll)            // &d_out[EMIS_N]
{
    const int b    = blockIdx.x;
    const int lane = threadIdx.x;
    const int* mrow = mask   + b * NS;
    const int* lrow = labels + b * NS;

    int lsum = 0;
    #pragma unroll
    for (int k = 0; k < 8; ++k) lsum += mrow[lane + k * 64];
    #pragma unroll
    for (int d = 32; d; d >>= 1) lsum += __shfl_xor(lsum, d);
    const int len = lsum;

    const float* base = ws + (size_t)b * WPB * PSTRIDE;
    const float* pa = base + (2 * lane)     * PSTRIDE;
    const float* pb = base + (2 * lane + 1) * PSTRIDE;
    float A[9], Bm[9];
    #pragma unroll
    for (int i = 0; i < 9; ++i) A[i]  = pa[i];
    #pragma unroll
    for (int i = 0; i < 9; ++i) Bm[i] = pb[i];
    float np = pa[9] + pb[9];

    float P[9];
    #pragma unroll
    for (int i = 0; i < 3; ++i)
        #pragma unroll
        for (int j = 0; j < 3; ++j)
            P[i * 3 + j] = lse3(A[i * 3 + 0] + Bm[0 + j],
                                A[i * 3 + 1] + Bm[3 + j],
                                A[i * 3 + 2] + Bm[6 + j]);

    #pragma unroll
    for (int d = 1; d < 64; d <<= 1) {
        float Q[9];
        #pragma unroll
        for (int i = 0; i < 9; ++i) Q[i] = __shfl_down(P[i], d);
        const bool valid = (lane + d) < 64;
        float R[9];
        #pragma unroll
        for (int i = 0; i < 3; ++i)
            #pragma unroll
            for (int j = 0; j < 3; ++j)
                R[i * 3 + j] = lse3(P[i * 3 + 0] + Q[0 + j],
                                    P[i * 3 + 1] + Q[3 + j],
                                    P[i * 3 + 2] + Q[6 + j]);
        #pragma unroll
        for (int i = 0; i < 9; ++i) P[i] = valid ? R[i] : P[i];
    }

    #pragma unroll
    for (int d = 32; d; d >>= 1) np += __shfl_xor(np, d);

    if (lane == 0) {
        const float* erow = emis + (size_t)b * NS * NT;
        const float a0 = startv[0] + erow[0];
        const float a1 = startv[1] + erow[1];
        const float a2 = startv[2] + erow[2];
        const float f0 = lse3(a0 + P[0], a1 + P[3], a2 + P[6]);
        const float f1 = lse3(a0 + P[1], a1 + P[4], a2 + P[7]);
        const float f2 = lse3(a0 + P[2], a1 + P[5], a2 + P[8]);
        const float logZ = lse3(f0 + endv[0], f1 + endv[1], f2 + endv[2]);

        const int tl = lrow[len - 1];
        const float num = np + endv[tl];   // start + e0 term already in np
        atomicAdd(nll, logZ - num);
    }
}

extern "C" void kernel_launch(void* const* d_in, const int* in_sizes, int n_in,
                              void* d_out, int out_size, void* d_ws, size_t ws_size,
                              hipStream_t stream) {
    const float* hidden = (const float*)d_in[0];
    const int*   labels = (const int*)  d_in[1];
    const int*   maskp  = (const int*)  d_in[2];
    const float* W      = (const float*)d_in[3];
    const float* bias   = (const float*)d_in[4];
    const float* trans  = (const float*)d_in[5];
    const float* startv = (const float*)d_in[6];
    const float* endv   = (const float*)d_in[7];
    float* out = (float*)d_out;
    float* ws  = (float*)d_ws;   // needs 8192 * 12 * 4 B = 384 KB

    emis_crf_kernel<<<2048, 256, 0, stream>>>(hidden, labels, maskp, W, bias,
                                              trans, startv, out, ws);
    crf_combine<<<NB, 64, 0, stream>>>(out, labels, maskp, startv, endv, ws,
                                       out + EMIS_N);
}

// Round 7
// 28.890 us; speedup vs baseline: 10.4158x; 1.0380x over previous
//
#include <hip/hip_runtime.h>
#include <math.h>

#define NB 64
#define NS 512
#define NH 768
#define NT 3
#define EMIS_N (NB * NS * NT)   // 98304
#define NEGINF (-1e30f)
#define PSTRIDE 12              // floats per block partial in ws
#define BPB 32                  // blocks per batch (512 rows / 16)

__device__ __forceinline__ float lse3(float a, float b, float c) {
    float m = fmaxf(fmaxf(a, b), c);
    return m + __logf(__expf(a - m) + __expf(b - m) + __expf(c - m));
}

// ---------------------------------------------------------------------------
// Kernel 1: emissions = relu(hidden @ W + b) fused with per-BLOCK CRF partial.
// r3 GEMV body (16 lanes/row, 4 rows/wave, W via L1). Label/mask loads hoisted
// to the top (issued before hidden loads -> latency hidden under the GEMV).
// Wave partials folded block-level in LDS: ws gets 1 partial per block.
// ---------------------------------------------------------------------------
__global__ __launch_bounds__(256) void emis_crf_kernel(
    const float* __restrict__ hidden,   // [NB*NS, NH]
    const int*   __restrict__ labels,   // [NB, NS]
    const int*   __restrict__ mask,     // [NB, NS]
    const float* __restrict__ W,        // [NH, NT]
    const float* __restrict__ bias,     // [NT]
    const float* __restrict__ trans,    // [NT, NT]
    const float* __restrict__ startv,   // [NT]
    float* __restrict__ out,            // emissions [NB*NS, NT], then nll
    float* __restrict__ ws)             // [2048 blocks][PSTRIDE]
{
    __shared__ float sP[4][12];

    const int tid  = threadIdx.x;
    const int lane = tid & 63;
    const int wv   = tid >> 6;               // wave 0..3
    const int wid  = blockIdx.x * 4 + wv;    // 0..8191
    const int sub  = lane & 15;              // h-chunk within row
    const int rsel = lane >> 4;              // which of the wave's 4 rows
    const int row  = wid * 4 + rsel;
    const int b    = row >> 9;               // batch
    const int p    = row & (NS - 1);         // position in sequence

    if (blockIdx.x == 0 && tid == 0) out[EMIS_N] = 0.0f;   // init nll acc

    // ---- hoisted scattered loads: issue FIRST, consumed in the tail ----
    const int* lrow = labels + b * NS;
    const int* mrow = mask   + b * NS;
    int mk = 0, labc = 0, labp = 0;
    if (sub == 0) {
        mk   = mrow[p];
        labc = lrow[p];
        labp = lrow[p - (p > 0 ? 1 : 0)];    // in-bounds; unused when p==0
    }

    // ---- GEMV (r3 body): hidden float4 stream x W from L1 ----
    const float* hrow = hidden + (size_t)row * NH;
    float a0 = 0.f, a1 = 0.f, a2 = 0.f;
    #pragma unroll
    for (int it = 0; it < 12; ++it) {
        const int h0 = it * 64 + sub * 4;
        const float4 x  = *reinterpret_cast<const float4*>(hrow + h0);
        const float4 q0 = *reinterpret_cast<const float4*>(W + h0 * 3);
        const float4 q1 = *reinterpret_cast<const float4*>(W + h0 * 3 + 4);
        const float4 q2 = *reinterpret_cast<const float4*>(W + h0 * 3 + 8);
        a0 = fmaf(x.x, q0.x, a0); a1 = fmaf(x.x, q0.y, a1); a2 = fmaf(x.x, q0.z, a2);
        a0 = fmaf(x.y, q0.w, a0); a1 = fmaf(x.y, q1.x, a1); a2 = fmaf(x.y, q1.y, a2);
        a0 = fmaf(x.z, q1.z, a0); a1 = fmaf(x.z, q1.w, a1); a2 = fmaf(x.z, q2.x, a2);
        a0 = fmaf(x.w, q2.y, a0); a1 = fmaf(x.w, q2.z, a1); a2 = fmaf(x.w, q2.w, a2);
    }
    #pragma unroll
    for (int d = 8; d; d >>= 1) {
        a0 += __shfl_xor(a0, d);
        a1 += __shfl_xor(a1, d);
        a2 += __shfl_xor(a2, d);
    }

    const float e0 = fmaxf(a0 + bias[0], 0.f);
    const float e1 = fmaxf(a1 + bias[1], 0.f);
    const float e2 = fmaxf(a2 + bias[2], 0.f);

    if (sub < 3) out[row * NT + sub] = (sub == 0) ? e0 : (sub == 1) ? e1 : e2;

    // ---- numerator term (labels/mask already in regs) ----
    float term = 0.f;
    if (sub == 0) {
        const float esel = (labc == 0) ? e0 : (labc == 1) ? e1 : e2;
        if (p == 0) {
            term = startv[labc] + esel;               // boundary term
        } else if (mk) {
            term = trans[labp * 3 + labc] + esel;     // step term
        }
    }

    // ---- compose the wave's 4 step matrices (9 active lanes) ----
    const int il = (lane < 9) ? (lane / 3) : 0;
    const int jl = (lane < 9) ? (lane % 3) : 0;
    const float tc0 = trans[jl], tc1 = trans[3 + jl], tc2 = trans[6 + jl];
    float Pv = (il == jl) ? 0.f : NEGINF;

    const int pbase = p & ~3;
    #pragma unroll
    for (int k = 0; k < 4; ++k) {
        const int src = k << 4;
        const float ee0 = __shfl(e0, src);
        const float ee1 = __shfl(e1, src);
        const float ee2 = __shfl(e2, src);
        const int   mm  = __shfl(mk, src);
        const float Pi0 = __shfl(Pv, il * 3 + 0);
        const float Pi1 = __shfl(Pv, il * 3 + 1);
        const float Pi2 = __shfl(Pv, il * 3 + 2);
        const float ej  = (jl == 0) ? ee0 : (jl == 1) ? ee1 : ee2;
        const float q   = lse3(Pi0 + tc0, Pi1 + tc1, Pi2 + tc2) + ej;
        const bool act  = ((pbase + k) >= 1) && (mm != 0);
        Pv = act ? q : Pv;
    }

    const float np = __shfl(term, 0) + __shfl(term, 16) +
                     __shfl(term, 32) + __shfl(term, 48);

    // ---- fold 4 wave partials -> 1 block partial (wave 0) ----
    if (lane < 9)  sP[wv][lane] = Pv;
    if (lane == 0) sP[wv][9]    = np;
    __syncthreads();
    if (wv == 0) {
        float Pb = (lane < 9) ? sP[0][lane] : 0.f;
        #pragma unroll
        for (int k = 1; k < 4; ++k) {
            const float Pi0 = __shfl(Pb, il * 3 + 0);
            const float Pi1 = __shfl(Pb, il * 3 + 1);
            const float Pi2 = __shfl(Pb, il * 3 + 2);
            const float q = lse3(Pi0 + sP[k][jl],
                                 Pi1 + sP[k][3 + jl],
                                 Pi2 + sP[k][6 + jl]);
            Pb = (lane < 9) ? q : Pb;
        }
        float* wp = ws + blockIdx.x * PSTRIDE;
        if (lane < 9)  wp[lane] = Pb;
        if (lane == 0) wp[9] = sP[0][9] + sP[1][9] + sP[2][9] + sP[3][9];
    }
}

// ---------------------------------------------------------------------------
// Kernel 2: combiner. One 64-lane block per batch: 32 block-partials, each on
// one lane (lanes>=32 hold identity), 5-step ordered shfl_down tree, boundary
// terms, one atomicAdd per batch. Partial loads issued first (independent).
// ---------------------------------------------------------------------------
__global__ __launch_bounds__(64) void crf_combine(
    const float* __restrict__ emis,     // [NB*NS, NT] (= d_out)
    const int*   __restrict__ labels,   // [NB, NS]
    const int*   __restrict__ mask,     // [NB, NS]
    const float* __restrict__ startv,   // [NT]
    const float* __restrict__ endv,     // [NT]
    const float* __restrict__ ws,       // block partials
    float* __restrict__ nll)            // &d_out[EMIS_N]
{
    const int b    = blockIdx.x;
    const int lane = threadIdx.x;

    // issue partial loads first
    float P[9] = {0.f, NEGINF, NEGINF, NEGINF, 0.f, NEGINF, NEGINF, NEGINF, 0.f};
    float np = 0.f;
    if (lane < BPB) {
        const float* pa = ws + ((size_t)b * BPB + lane) * PSTRIDE;
        #pragma unroll
        for (int i = 0; i < 9; ++i) P[i] = pa[i];
        np = pa[9];
    }

    const int* mrow = mask   + b * NS;
    const int* lrow = labels + b * NS;
    int lsum = 0;
    #pragma unroll
    for (int k = 0; k < 8; ++k) lsum += mrow[lane + k * 64];
    #pragma unroll
    for (int d = 32; d; d >>= 1) lsum += __shfl_xor(lsum, d);
    const int len = lsum;

    // ordered tree over 32 partials (lane l covers blocks [l, l+d))
    #pragma unroll
    for (int d = 1; d < BPB; d <<= 1) {
        float Q[9];
        #pragma unroll
        for (int i = 0; i < 9; ++i) Q[i] = __shfl_down(P[i], d);
        const bool valid = (lane + d) < BPB;
        float R[9];
        #pragma unroll
        for (int i = 0; i < 3; ++i)
            #pragma unroll
            for (int j = 0; j < 3; ++j)
                R[i * 3 + j] = lse3(P[i * 3 + 0] + Q[0 + j],
                                    P[i * 3 + 1] + Q[3 + j],
                                    P[i * 3 + 2] + Q[6 + j]);
        #pragma unroll
        for (int i = 0; i < 9; ++i) P[i] = valid ? R[i] : P[i];
    }

    #pragma unroll
    for (int d = 32; d; d >>= 1) np += __shfl_xor(np, d);

    if (lane == 0) {
        const float* erow = emis + (size_t)b * NS * NT;
        const float a0 = startv[0] + erow[0];
        const float a1 = startv[1] + erow[1];
        const float a2 = startv[2] + erow[2];
        const float f0 = lse3(a0 + P[0], a1 + P[3], a2 + P[6]);
        const float f1 = lse3(a0 + P[1], a1 + P[4], a2 + P[7]);
        const float f2 = lse3(a0 + P[2], a1 + P[5], a2 + P[8]);
        const float logZ = lse3(f0 + endv[0], f1 + endv[1], f2 + endv[2]);

        const int tl = lrow[len - 1];
        const float num = np + endv[tl];   // start + e0 term already in np
        atomicAdd(nll, logZ - num);
    }
}

extern "C" void kernel_launch(void* const* d_in, const int* in_sizes, int n_in,
                              void* d_out, int out_size, void* d_ws, size_t ws_size,
                              hipStream_t stream) {
    const float* hidden = (const float*)d_in[0];
    const int*   labels = (const int*)  d_in[1];
    const int*   maskp  = (const int*)  d_in[2];
    const float* W      = (const float*)d_in[3];
    const float* bias   = (const float*)d_in[4];
    const float* trans  = (const float*)d_in[5];
    const float* startv = (const float*)d_in[6];
    const float* endv   = (const float*)d_in[7];
    float* out = (float*)d_out;
    float* ws  = (float*)d_ws;   // needs 2048 * 12 * 4 B = 96 KB

    emis_crf_kernel<<<2048, 256, 0, stream>>>(hidden, labels, maskp, W, bias,
                                              trans, startv, out, ws);
    crf_combine<<<NB, 64, 0, stream>>>(out, labels, maskp, startv, endv, ws,
                                       out + EMIS_N);
}